// Round 18
// baseline (307.563 us; speedup 1.0000x reference)
//
#include <hip/hip_runtime.h>
#include <math.h>

#define CUTR 5.0f
#define TL 2048
#define NBASIS 32
#define HSC 16.0f
#define TSC 16.0f
#define VSC 64.0f
#define INV_HT (1.0f / (HSC * TSC))
#define INV_HTV (1.0f / (HSC * TSC * VSC))

typedef __attribute__((ext_vector_type(8))) short bf16x8;
typedef __attribute__((ext_vector_type(4))) float f32x4;
typedef __attribute__((ext_vector_type(2))) float f32x2;

struct U3 { uint x, y, z; };
struct U2 { uint x, y; };

__device__ __forceinline__ float silu_f(float x) { return x / (1.0f + expf(-x)); }
__device__ __forceinline__ ushort f2bf(float x) {
  uint b = __float_as_uint(x);
  uint r = (b + 0x7FFFu + ((b >> 16) & 1u)) >> 16;
  return (ushort)r;
}
__device__ __forceinline__ float bf2f(ushort u) { return __uint_as_float((uint)u << 16); }
__device__ __forceinline__ uchar f2fp8(float x) {
  return (uchar)(__builtin_amdgcn_cvt_pk_fp8_f32(x, 0.0f, 0, false) & 0xff);
}
__device__ __forceinline__ f32x2 fp8lo(uint u) {
  return __builtin_amdgcn_cvt_pk_f32_fp8((int)u, false);
}
__device__ __forceinline__ f32x2 fp8hi(uint u) {
  return __builtin_amdgcn_cvt_pk_f32_fp8((int)u, true);
}

// ---------------- radial table (fp8, interleaved) ----------------
__global__ __launch_bounds__(384) void table_kernel(const float* __restrict__ f_w,
                                                    const float* __restrict__ f_b,
                                                    uchar* __restrict__ tab) {
  __shared__ float fws[NBASIS * 384];
  __shared__ float rbf[8][NBASIS];
  __shared__ float gv[8];
  int tid = threadIdx.x;
  int bi = blockIdx.x;
  int l = bi >> 8, tb = bi & 255;
  for (int i = tid; i < NBASIS * 384; i += 384) fws[i] = f_w[l * NBASIS * 384 + i];
  if (tid < 256) {
    int tt = tid >> 5, k = tid & 31;
    float len = (float)(tb * 8 + tt) * (CUTR / (float)(TL - 1));
    const float gamma = (31.0f / 5.0f) * (31.0f / 5.0f);
    float c = 5.0f * (float)k / 31.0f;
    float d = len - c;
    rbf[tt][k] = expf(-gamma * d * d);
    if (k == 0) {
      float s = len * (1.0f / CUTR);
      gv[tt] = (s < 1.0f) ? expf(1.0f - 1.0f / (1.0f - s * s)) : 0.0f;
    }
  }
  __syncthreads();
  int j = tid % 384;
  int b = j >> 7, ch = j & 127;
  float fb = f_b[l * 384 + j];
  for (int tt = 0; tt < 8; ++tt) {
    float acc = 0.0f;
#pragma unroll
    for (int k = 0; k < NBASIS; ++k) acc += rbf[tt][k] * fws[k * 384 + j];
    float g = gv[tt];
    tab[((size_t)l * TL + (size_t)(tb * 8 + tt)) * 512 + (ch >> 1) * 8 + b * 2 + (ch & 1)] =
        f2fp8(g * (g * acc + fb) * TSC);
  }
}

// ---------------- init: emb | wconv | count (no LDS) ----------------
__global__ __launch_bounds__(256) void init_kernel(
    const int* __restrict__ z, const float* __restrict__ emb, float* __restrict__ scalar,
    ushort* __restrict__ sbf, const float* __restrict__ m_w1, const float* __restrict__ m_w2,
    const float* __restrict__ u_w, const float* __restrict__ v_w,
    const float* __restrict__ up_w1, const float* __restrict__ up_w2,
    const float* __restrict__ r_w1, ushort* __restrict__ wt, const float* __restrict__ pos,
    const int* __restrict__ ei, const float* __restrict__ shifts, int* __restrict__ counts,
    int N, int E) {
  int tid = threadIdx.x;
  int bi = blockIdx.x;
  int nbEmb = (N * 128 + 255) / 256;
  int nbW = (548864 + 255) / 256;
  if (bi < nbEmb) {
    int idx = bi * 256 + tid;
    if (idx >= N * 128) return;
    int n = idx >> 7, j = idx & 127;
    float v = emb[z[n] * 128 + j];
    scalar[idx] = v;
    sbf[idx] = f2bf(v);
    return;
  }
  bi -= nbEmb;
  if (bi < nbW) {
    int idx = bi * 256 + tid;
    if (idx >= 548864) return;
    float v;
    if (idx >= 540672) {
      int t = idx - 540672;
      int n = t >> 7, k = t & 127;
      v = r_w1[k * 64 + n];
    } else {
      int l = idx / 180224, local = idx % 180224;
      if (local < 16384) {
        int n = local >> 7, k = local & 127;
        v = m_w1[l * 16384 + k * 128 + n];
      } else if (local < 65536) {
        int t = local - 16384;
        int n = t >> 7, k = t & 127;
        v = m_w2[l * 49152 + k * 384 + n];
      } else if (local < 98304) {
        int t = local - 65536;
        int n = t >> 7, k = t & 127;
        v = (n < 128) ? u_w[l * 16384 + k * 128 + n] : v_w[l * 16384 + k * 128 + (n - 128)];
      } else if (local < 131072) {
        int t = local - 98304;
        int n = t >> 8, k = t & 255;
        v = up_w1[l * 32768 + k * 128 + n];
      } else {
        int t = local - 131072;
        int n = t >> 7, k = t & 127;
        v = up_w2[l * 49152 + k * 384 + n];
      }
    }
    wt[idx] = f2bf(v);
    return;
  }
  bi -= nbW;
  {
    int e = bi * 256 + tid;
    if (e >= E) return;
    int r = ei[e], c = ei[E + e];
    float dx = pos[c * 3 + 0] - pos[r * 3 + 0] + shifts[e * 3 + 0];
    float dy = pos[c * 3 + 1] - pos[r * 3 + 1] + shifts[e * 3 + 1];
    float dz = pos[c * 3 + 2] - pos[r * 3 + 2] + shifts[e * 3 + 2];
    float len = sqrtf(dx * dx + dy * dy + dz * dz + 1e-12f);
    if (len < CUTR) atomicAdd(&counts[r], 1);
  }
}

// ---------------- scan + descending-degree order ----------------
__global__ __launch_bounds__(1024) void scan_kernel(const int* __restrict__ counts,
                                                    int* __restrict__ offs,
                                                    int* __restrict__ cursor,
                                                    int* __restrict__ order, int N) {
  __shared__ int sm[1024];
  __shared__ int hist[128];
  __shared__ int hoff[128];
  int tid = threadIdx.x;
  int CH = (N + 1023) / 1024;
  int base = tid * CH;
  int sum = 0;
  for (int i = 0; i < CH; i++) sum += (base + i < N) ? counts[base + i] : 0;
  sm[tid] = sum;
  __syncthreads();
  for (int o = 1; o < 1024; o <<= 1) {
    int v = (tid >= o) ? sm[tid - o] : 0;
    __syncthreads();
    sm[tid] += v;
    __syncthreads();
  }
  int run = sm[tid] - sum;
  for (int i = 0; i < CH; i++) {
    if (base + i < N) {
      offs[base + i] = run;
      cursor[base + i] = run;
      run += counts[base + i];
    }
  }
  if (tid == 1023) offs[N] = sm[1023];
  if (tid < 128) hist[tid] = 0;
  __syncthreads();
  for (int i = 0; i < CH; i++) {
    int n = base + i;
    if (n < N) {
      int d = counts[n];
      if (d > 127) d = 127;
      atomicAdd(&hist[d], 1);
    }
  }
  __syncthreads();
  if (tid == 0) {
    int r = 0;
    for (int d = 127; d >= 0; --d) {
      hoff[d] = r;
      r += hist[d];
    }
  }
  __syncthreads();
  for (int i = 0; i < CH; i++) {
    int n = base + i;
    if (n < N) {
      int d = counts[n];
      if (d > 127) d = 127;
      int pos = atomicAdd(&hoff[d], 1);
      order[pos] = n;
    }
  }
}

__global__ void fill_kernel(const float* __restrict__ pos, const int* __restrict__ ei,
                            const float* __restrict__ shifts, int* __restrict__ cursor,
                            float4* __restrict__ pk, int E) {
  int e = blockIdx.x * 256 + threadIdx.x;
  if (e >= E) return;
  int r = ei[e], c = ei[E + e];
  float dx = pos[c * 3 + 0] - pos[r * 3 + 0] + shifts[e * 3 + 0];
  float dy = pos[c * 3 + 1] - pos[r * 3 + 1] + shifts[e * 3 + 1];
  float dz = pos[c * 3 + 2] - pos[r * 3 + 2] + shifts[e * 3 + 2];
  float len = sqrtf(dx * dx + dy * dy + dz * dz + 1e-12f);
  if (len >= CUTR) return;
  float inv = 1.0f / len;
  float x = len * ((float)(TL - 1) / CUTR);
  int ib = (int)(x + 0.5f);
  if (ib > TL - 1) ib = TL - 1;
  int p = atomicAdd(&cursor[r], 1);
  pk[p] = make_float4(__int_as_float(c | (ib << 14)), dx * inv, dy * inv, dz * inv);
}

// ---------------- fused message: 1 wave/node, software-pipelined fp8 gathers ---------------
template <bool FIRST>
__global__ __launch_bounds__(256) void message_kernel(
    const int* __restrict__ offs, const int* __restrict__ order, const float4* __restrict__ pk,
    const uchar* __restrict__ hv8, const uchar* __restrict__ tab8, float* __restrict__ scalar,
    ushort* __restrict__ sbf, float* __restrict__ vec, ushort* __restrict__ vbout, int N) {
  int lane = threadIdx.x & 63;
  int idx = blockIdx.x * 4 + (threadIdx.x >> 6);
  if (idx >= N) return;
  int n = order[idx];
  int p0 = offs[n], p1 = offs[n + 1];
  f32x2 aS = {0.f, 0.f};
  f32x2 aW0 = {0.f, 0.f}, aW1 = {0.f, 0.f}, aW2 = {0.f, 0.f};
  f32x2 aD0 = {0.f, 0.f}, aD1 = {0.f, 0.f}, aD2 = {0.f, 0.f};
  // batch = 2 edges; 2-stage pipeline: gathers for batch k+1 issued while computing batch k
  int p = p0;
  bool a0 = p < p1, b0 = p + 1 < p1;
  float4 dA0, dB0;
  if (a0) dA0 = pk[p];
  if (b0) dB0 = pk[p + 1];
  // gathers for batch 0
  U3 hvA0, hvB0;
  U2 tA0, tB0;
  if (a0) {
    int bits = __float_as_int(dA0.x);
    int col = bits & 16383, ib = bits >> 14;
    if (FIRST) {
      U2 t = *(const U2*)(hv8 + (size_t)col * 768 + lane * 12);
      hvA0.x = t.x; hvA0.y = t.y; hvA0.z = 0;
    } else {
      hvA0 = *(const U3*)(hv8 + (size_t)col * 768 + lane * 12);
    }
    tA0 = *(const U2*)(tab8 + (size_t)ib * 512 + lane * 8);
  }
  if (b0) {
    int bits = __float_as_int(dB0.x);
    int col = bits & 16383, ib = bits >> 14;
    if (FIRST) {
      U2 t = *(const U2*)(hv8 + (size_t)col * 768 + lane * 12);
      hvB0.x = t.x; hvB0.y = t.y; hvB0.z = 0;
    } else {
      hvB0 = *(const U3*)(hv8 + (size_t)col * 768 + lane * 12);
    }
    tB0 = *(const U2*)(tab8 + (size_t)ib * 512 + lane * 8);
  }
  // descriptors for batch 1
  int pn = p + 2;
  bool a1 = pn < p1, b1 = pn + 1 < p1;
  float4 dA1, dB1;
  if (a1) dA1 = pk[pn];
  if (b1) dB1 = pk[pn + 1];

  while (a0) {
    // issue gathers for batch 1 (descriptors already resident)
    U3 hvA1, hvB1;
    U2 tA1, tB1;
    if (a1) {
      int bits = __float_as_int(dA1.x);
      int col = bits & 16383, ib = bits >> 14;
      if (FIRST) {
        U2 t = *(const U2*)(hv8 + (size_t)col * 768 + lane * 12);
        hvA1.x = t.x; hvA1.y = t.y; hvA1.z = 0;
      } else {
        hvA1 = *(const U3*)(hv8 + (size_t)col * 768 + lane * 12);
      }
      tA1 = *(const U2*)(tab8 + (size_t)ib * 512 + lane * 8);
    }
    if (b1) {
      int bits = __float_as_int(dB1.x);
      int col = bits & 16383, ib = bits >> 14;
      if (FIRST) {
        U2 t = *(const U2*)(hv8 + (size_t)col * 768 + lane * 12);
        hvB1.x = t.x; hvB1.y = t.y; hvB1.z = 0;
      } else {
        hvB1 = *(const U3*)(hv8 + (size_t)col * 768 + lane * 12);
      }
      tB1 = *(const U2*)(tab8 + (size_t)ib * 512 + lane * 8);
    }
    // prefetch descriptors for batch 2
    int pnn = pn + 2;
    bool a2 = pnn < p1, b2 = pnn + 1 < p1;
    float4 dA2, dB2;
    if (a2) dA2 = pk[pnn];
    if (b2) dB2 = pk[pnn + 1];
    // compute batch 0
    {
      f32x2 h1 = fp8lo(hvA0.x), h2 = fp8hi(hvA0.x);
      f32x2 h3 = fp8lo(hvA0.y);
      f32x2 t1 = fp8lo(tA0.x), t2 = fp8hi(tA0.x), t3 = fp8lo(tA0.y);
      aS += h1 * t1;
      f32x2 w3 = h3 * t3;
      if (!FIRST) {
        f32x2 v0 = fp8hi(hvA0.y), v1 = fp8lo(hvA0.z), v2 = fp8hi(hvA0.z);
        f32x2 w2 = h2 * t2;
        aW0 += v0 * w2;
        aW1 += v1 * w2;
        aW2 += v2 * w2;
      }
      aD0 += w3 * dA0.y;
      aD1 += w3 * dA0.z;
      aD2 += w3 * dA0.w;
    }
    if (b0) {
      f32x2 h1 = fp8lo(hvB0.x), h2 = fp8hi(hvB0.x);
      f32x2 h3 = fp8lo(hvB0.y);
      f32x2 t1 = fp8lo(tB0.x), t2 = fp8hi(tB0.x), t3 = fp8lo(tB0.y);
      aS += h1 * t1;
      f32x2 w3 = h3 * t3;
      if (!FIRST) {
        f32x2 v0 = fp8hi(hvB0.y), v1 = fp8lo(hvB0.z), v2 = fp8hi(hvB0.z);
        f32x2 w2 = h2 * t2;
        aW0 += v0 * w2;
        aW1 += v1 * w2;
        aW2 += v2 * w2;
      }
      aD0 += w3 * dB0.y;
      aD1 += w3 * dB0.z;
      aD2 += w3 * dB0.w;
    }
    // shift pipeline
    dA0 = dA1; dB0 = dB1;
    hvA0 = hvA1; hvB0 = hvB1;
    tA0 = tA1; tB0 = tB1;
    a0 = a1; b0 = b1;
    dA1 = dA2; dB1 = dB2;
    a1 = a2; b1 = b2;
    pn = pnn;
  }
  f32x2 sS = aS * INV_HT;
  f32x2 sV0 = aD0 * INV_HT, sV1 = aD1 * INV_HT, sV2 = aD2 * INV_HT;
  if (!FIRST) {
    sV0 += aW0 * INV_HTV;
    sV1 += aW1 * INV_HTV;
    sV2 += aW2 * INV_HTV;
  }
  float2* sp = (float2*)(scalar + (size_t)n * 128) + lane;
  float2 sv = *sp;
  sv.x += sS.x;
  sv.y += sS.y;
  *sp = sv;
  ((uint*)(sbf + (size_t)n * 128))[lane] = (uint)f2bf(sv.x) | ((uint)f2bf(sv.y) << 16);
  float2* vp0 = (float2*)(vec + (size_t)n * 384) + lane;
  float2* vp1 = (float2*)(vec + (size_t)n * 384 + 128) + lane;
  float2* vp2 = (float2*)(vec + (size_t)n * 384 + 256) + lane;
  float2 v0, v1, v2;
  if (FIRST) {
    v0 = make_float2(sV0.x, sV0.y);
    v1 = make_float2(sV1.x, sV1.y);
    v2 = make_float2(sV2.x, sV2.y);
  } else {
    v0 = *vp0; v1 = *vp1; v2 = *vp2;
    v0.x += sV0.x; v0.y += sV0.y;
    v1.x += sV1.x; v1.y += sV1.y;
    v2.x += sV2.x; v2.y += sV2.y;
  }
  *vp0 = v0; *vp1 = v1; *vp2 = v2;
  uint* ob = (uint*)(vbout + (size_t)n * 384);
  ob[lane] = (uint)f2bf(v0.x) | ((uint)f2bf(v0.y) << 16);
  ob[lane + 64] = (uint)f2bf(v1.x) | ((uint)f2bf(v1.y) << 16);
  ob[lane + 128] = (uint)f2bf(v2.x) | ((uint)f2bf(v2.y) << 16);
}

// ---------------- message MLP (layer 0 only): writes h-part of hv8 ----------------
__global__ __launch_bounds__(512) void mlp_kernel(const ushort* __restrict__ A,
                                                  const ushort* __restrict__ W1T,
                                                  const float* __restrict__ b1,
                                                  const ushort* __restrict__ W2T,
                                                  const float* __restrict__ b2,
                                                  uchar* __restrict__ out, int M) {
  __shared__ ushort As[32 * 128];
  __shared__ ushort Bs[128 * 128];
  __shared__ ushort Hs[32 * 128];
  int tid = threadIdx.x;
  int lane = tid & 63, w = tid >> 6;
  int mh = w >> 2, wc = w & 3;
  int m0 = blockIdx.x * 32;
  int cl = lane & 15, rq = lane >> 4;
  int ra = mh * 16 + cl;
  f32x4 acc[2] = {};
  {
    {
      int row = tid >> 4, ch = tid & 15;
      uint4 av = make_uint4(0, 0, 0, 0);
      if (m0 + row < M) av = *(const uint4*)(A + (size_t)(m0 + row) * 128 + ch * 8);
      *(uint4*)(&As[row * 128 + ((ch ^ (row & 7)) * 8)]) = av;
    }
#pragma unroll
    for (int r = 0; r < 4; ++r) {
      int c = tid + r * 512;
      int row = c >> 4, ch = c & 15;
      uint4 bv = *(const uint4*)(W1T + (size_t)row * 128 + ch * 8);
      *(uint4*)(&Bs[row * 128 + ((ch ^ (row & 7)) * 8)]) = bv;
    }
    __syncthreads();
#pragma unroll
    for (int ks = 0; ks < 4; ++ks) {
      int ch = ks * 4 + rq;
      bf16x8 a = *(bf16x8*)&As[ra * 128 + ((ch ^ (ra & 7)) * 8)];
#pragma unroll
      for (int ns = 0; ns < 2; ++ns) {
        int rb = wc * 32 + ns * 16 + cl;
        bf16x8 b = *(bf16x8*)&Bs[rb * 128 + ((ch ^ (rb & 7)) * 8)];
        acc[ns] = __builtin_amdgcn_mfma_f32_16x16x32_bf16(a, b, acc[ns], 0, 0, 0);
      }
    }
  }
#pragma unroll
  for (int ns = 0; ns < 2; ++ns) {
    int hcol = wc * 32 + ns * 16 + cl;
    float bv = b1[hcol];
    int chunk = hcol >> 3, el = hcol & 7;
#pragma unroll
    for (int j = 0; j < 4; ++j) {
      int hr = mh * 16 + rq * 4 + j;
      float v = silu_f(acc[ns][j] + bv);
      Hs[hr * 128 + ((chunk ^ (hr & 7)) * 8) + el] = f2bf(v);
    }
  }
  __syncthreads();
  for (int nt = 0; nt < 3; ++nt) {
#pragma unroll
    for (int r = 0; r < 4; ++r) {
      int c = tid + r * 512;
      int row = c >> 4, ch = c & 15;
      uint4 bv = *(const uint4*)(W2T + (size_t)(nt * 128 + row) * 128 + ch * 8);
      *(uint4*)(&Bs[row * 128 + ((ch ^ (row & 7)) * 8)]) = bv;
    }
    __syncthreads();
    f32x4 acc2[2] = {};
#pragma unroll
    for (int ks = 0; ks < 4; ++ks) {
      int ch = ks * 4 + rq;
      bf16x8 a = *(bf16x8*)&Hs[ra * 128 + ((ch ^ (ra & 7)) * 8)];
#pragma unroll
      for (int ns = 0; ns < 2; ++ns) {
        int rb = wc * 32 + ns * 16 + cl;
        bf16x8 b = *(bf16x8*)&Bs[rb * 128 + ((ch ^ (rb & 7)) * 8)];
        acc2[ns] = __builtin_amdgcn_mfma_f32_16x16x32_bf16(a, b, acc2[ns], 0, 0, 0);
      }
    }
#pragma unroll
    for (int ns = 0; ns < 2; ++ns) {
      int ch = wc * 32 + ns * 16 + cl;
      float bv = b2[nt * 128 + ch];
#pragma unroll
      for (int j = 0; j < 4; ++j) {
        int m = m0 + mh * 16 + rq * 4 + j;
        if (m >= M) continue;
        out[(size_t)m * 768 + (ch >> 1) * 12 + nt * 2 + (ch & 1)] =
            f2fp8((acc2[ns][j] + bv) * HSC);
      }
    }
    __syncthreads();
  }
}

// ---------------- fused update MLP + combine (+ next-layer MLP unless LAST) ----------------
template <bool LAST>
__global__ __launch_bounds__(512) void mlp2_kernel(
    const ushort* __restrict__ sbf_in, const ushort* __restrict__ W1T,
    const float* __restrict__ b1, const ushort* __restrict__ W2T, const float* __restrict__ b2,
    const ushort* __restrict__ uvvv, float* __restrict__ scalar, ushort* __restrict__ sbf,
    float* __restrict__ vec, uchar* __restrict__ hv8, const ushort* __restrict__ W1nT,
    const float* __restrict__ b1n, const ushort* __restrict__ W2nT,
    const float* __restrict__ b2n, int M) {
  __shared__ ushort As[16 * 128];
  __shared__ ushort Bs[128 * 128];
  __shared__ ushort Hs[16 * 128];
  int tid = threadIdx.x;
  int lane = tid & 63, w = tid >> 6;
  int m0 = blockIdx.x * 16;
  int cl = lane & 15, rq = lane >> 4;
  int rb = w * 16 + cl;
  f32x4 acc = {};
  for (int k0 = 0; k0 < 256; k0 += 128) {
    __syncthreads();
    if (tid < 256) {
      int row = tid >> 4, ch = tid & 15;
      uint4 av = make_uint4(0, 0, 0, 0);
      if (m0 + row < M) {
        if (k0 == 0) {
          av = *(const uint4*)(sbf_in + (size_t)(m0 + row) * 128 + ch * 8);
        } else {
          const ushort* ub = uvvv + (size_t)(m0 + row) * 768 + 128 + ch * 8;
          bf16x8 x0 = *(const bf16x8*)(ub);
          bf16x8 x1 = *(const bf16x8*)(ub + 256);
          bf16x8 x2 = *(const bf16x8*)(ub + 512);
          ushort pkv[8];
#pragma unroll
          for (int e = 0; e < 8; ++e) {
            float a = bf2f((ushort)x0[e]), bb = bf2f((ushort)x1[e]), cc = bf2f((ushort)x2[e]);
            pkv[e] = f2bf(sqrtf(a * a + bb * bb + cc * cc + 1e-8f));
          }
          av = *(uint4*)pkv;
        }
      }
      *(uint4*)(&As[row * 128 + ((ch ^ (row & 7)) * 8)]) = av;
    }
#pragma unroll
    for (int r = 0; r < 4; ++r) {
      int c = tid + r * 512;
      int row = c >> 4, ch = c & 15;
      uint4 bv = *(const uint4*)(W1T + (size_t)row * 256 + k0 + ch * 8);
      *(uint4*)(&Bs[row * 128 + ((ch ^ (row & 7)) * 8)]) = bv;
    }
    __syncthreads();
#pragma unroll
    for (int ks = 0; ks < 4; ++ks) {
      int ch = ks * 4 + rq;
      bf16x8 a = *(bf16x8*)&As[cl * 128 + ((ch ^ (cl & 7)) * 8)];
      bf16x8 b = *(bf16x8*)&Bs[rb * 128 + ((ch ^ (rb & 7)) * 8)];
      acc = __builtin_amdgcn_mfma_f32_16x16x32_bf16(a, b, acc, 0, 0, 0);
    }
  }
  {
    int hcol = w * 16 + cl;
    float bv = b1[hcol];
    int chunk = hcol >> 3, el = hcol & 7;
#pragma unroll
    for (int j = 0; j < 4; ++j) {
      int hr = rq * 4 + j;
      Hs[hr * 128 + ((chunk ^ (hr & 7)) * 8) + el] = f2bf(silu_f(acc[j] + bv));
    }
  }
  __syncthreads();
  f32x4 aReg[3];
  for (int nt = 0; nt < 3; ++nt) {
#pragma unroll
    for (int r = 0; r < 4; ++r) {
      int c = tid + r * 512;
      int row = c >> 4, ch = c & 15;
      uint4 bv = *(const uint4*)(W2T + (size_t)(nt * 128 + row) * 128 + ch * 8);
      *(uint4*)(&Bs[row * 128 + ((ch ^ (row & 7)) * 8)]) = bv;
    }
    __syncthreads();
    f32x4 acc2 = {};
#pragma unroll
    for (int ks = 0; ks < 4; ++ks) {
      int ch = ks * 4 + rq;
      bf16x8 a = *(bf16x8*)&Hs[cl * 128 + ((ch ^ (cl & 7)) * 8)];
      bf16x8 b = *(bf16x8*)&Bs[rb * 128 + ((ch ^ (rb & 7)) * 8)];
      acc2 = __builtin_amdgcn_mfma_f32_16x16x32_bf16(a, b, acc2, 0, 0, 0);
    }
    aReg[nt] = acc2;
    __syncthreads();
  }
  {
    int chOff = w * 16 + cl;
    float b2a = b2[chOff], b2b = b2[128 + chOff], b2c = b2[256 + chOff];
#pragma unroll
    for (int j = 0; j < 4; ++j) {
      int nn = m0 + rq * 4 + j;
      if (nn >= M) continue;
      float a1 = aReg[0][j] + b2a;
      float a2 = aReg[1][j] + b2b;
      float a3 = aReg[2][j] + b2c;
      const ushort* ub = uvvv + (size_t)nn * 768;
      float uv0 = bf2f(ub[chOff]), vv0 = bf2f(ub[128 + chOff]);
      float uv1 = bf2f(ub[256 + chOff]), vv1 = bf2f(ub[384 + chOff]);
      float uv2 = bf2f(ub[512 + chOff]), vv2 = bf2f(ub[640 + chOff]);
      float dot = uv0 * vv0 + uv1 * vv1 + uv2 * vv2;
      size_t si = (size_t)nn * 128 + chOff;
      float s = scalar[si] + a1 + a2 * dot;
      scalar[si] = s;
      ushort sb = f2bf(s);
      sbf[si] = sb;
      if (!LAST) {
        int lr = rq * 4 + j;
        As[lr * 128 + (((chOff >> 3) ^ (lr & 7)) * 8) + (chOff & 7)] = sb;
        size_t vb = (size_t)nn * 384 + chOff;
        float nv0 = vec[vb] + a3 * uv0;
        float nv1 = vec[vb + 128] + a3 * uv1;
        float nv2 = vec[vb + 256] + a3 * uv2;
        vec[vb] = nv0;
        vec[vb + 128] = nv1;
        vec[vb + 256] = nv2;
        size_t hb = (size_t)nn * 768 + (chOff >> 1) * 12 + 6 + (chOff & 1);
        hv8[hb] = f2fp8(nv0 * VSC);
        hv8[hb + 2] = f2fp8(nv1 * VSC);
        hv8[hb + 4] = f2fp8(nv2 * VSC);
      }
    }
  }
  if (LAST) return;
#pragma unroll
  for (int r = 0; r < 4; ++r) {
    int c = tid + r * 512;
    int row = c >> 4, ch = c & 15;
    uint4 bv = *(const uint4*)(W1nT + (size_t)row * 128 + ch * 8);
    *(uint4*)(&Bs[row * 128 + ((ch ^ (row & 7)) * 8)]) = bv;
  }
  __syncthreads();
  f32x4 acc3 = {};
#pragma unroll
  for (int ks = 0; ks < 4; ++ks) {
    int ch = ks * 4 + rq;
    bf16x8 a = *(bf16x8*)&As[cl * 128 + ((ch ^ (cl & 7)) * 8)];
    bf16x8 b = *(bf16x8*)&Bs[rb * 128 + ((ch ^ (rb & 7)) * 8)];
    acc3 = __builtin_amdgcn_mfma_f32_16x16x32_bf16(a, b, acc3, 0, 0, 0);
  }
  __syncthreads();
  {
    int hcol = w * 16 + cl;
    float bv = b1n[hcol];
    int chunk = hcol >> 3, el = hcol & 7;
#pragma unroll
    for (int j = 0; j < 4; ++j) {
      int hr = rq * 4 + j;
      Hs[hr * 128 + ((chunk ^ (hr & 7)) * 8) + el] = f2bf(silu_f(acc3[j] + bv));
    }
  }
  __syncthreads();
  for (int nt = 0; nt < 3; ++nt) {
#pragma unroll
    for (int r = 0; r < 4; ++r) {
      int c = tid + r * 512;
      int row = c >> 4, ch = c & 15;
      uint4 bv = *(const uint4*)(W2nT + (size_t)(nt * 128 + row) * 128 + ch * 8);
      *(uint4*)(&Bs[row * 128 + ((ch ^ (row & 7)) * 8)]) = bv;
    }
    __syncthreads();
    f32x4 acc4 = {};
#pragma unroll
    for (int ks = 0; ks < 4; ++ks) {
      int ch = ks * 4 + rq;
      bf16x8 a = *(bf16x8*)&Hs[cl * 128 + ((ch ^ (cl & 7)) * 8)];
      bf16x8 b = *(bf16x8*)&Bs[rb * 128 + ((ch ^ (rb & 7)) * 8)];
      acc4 = __builtin_amdgcn_mfma_f32_16x16x32_bf16(a, b, acc4, 0, 0, 0);
    }
    {
      int ch = w * 16 + cl;
      float bv = b2n[nt * 128 + ch];
#pragma unroll
      for (int j = 0; j < 4; ++j) {
        int m = m0 + rq * 4 + j;
        if (m >= M) continue;
        hv8[(size_t)m * 768 + (ch >> 1) * 12 + nt * 2 + (ch & 1)] =
            f2fp8((acc4[j] + bv) * HSC);
      }
    }
    __syncthreads();
  }
}

// ---------------- bf16 MFMA GEMM: C = A[M,K] @ WT[N,K]^T -> bf16 ----------------
__global__ __launch_bounds__(256) void gemm_kernel(const ushort* __restrict__ A,
                                                   const ushort* __restrict__ WT,
                                                   ushort* __restrict__ Cout, int M, int K,
                                                   int Nn) {
  __shared__ ushort As[64 * 128];
  __shared__ ushort Bs[64 * 128];
  int tid = threadIdx.x;
  int m0 = blockIdx.x * 64, n0 = blockIdx.y * 64;
  int lane = tid & 63, w = tid >> 6, wr = w >> 1, wc = w & 1;
  f32x4 acc[2][2] = {};
  for (int k0 = 0; k0 < K; k0 += 128) {
    __syncthreads();
#pragma unroll
    for (int r = 0; r < 4; ++r) {
      int c = tid + r * 256;
      int row = c >> 4, col16 = c & 15;
      uint4 av = make_uint4(0, 0, 0, 0);
      if (m0 + row < M) av = *(const uint4*)(A + (size_t)(m0 + row) * K + k0 + col16 * 8);
      *(uint4*)(&As[row * 128 + ((col16 ^ (row & 7)) * 8)]) = av;
      uint4 bv = *(const uint4*)(WT + (size_t)(n0 + row) * K + k0 + col16 * 8);
      *(uint4*)(&Bs[row * 128 + ((col16 ^ (row & 7)) * 8)]) = bv;
    }
    __syncthreads();
#pragma unroll
    for (int ks = 0; ks < 4; ++ks) {
      int ch = ks * 4 + (lane >> 4);
      int ra0 = wr * 32 + (lane & 15), ra1 = ra0 + 16;
      int rb0 = wc * 32 + (lane & 15), rb1 = rb0 + 16;
      bf16x8 a0 = *(bf16x8*)&As[ra0 * 128 + ((ch ^ (ra0 & 7)) * 8)];
      bf16x8 a1 = *(bf16x8*)&As[ra1 * 128 + ((ch ^ (ra1 & 7)) * 8)];
      bf16x8 b0 = *(bf16x8*)&Bs[rb0 * 128 + ((ch ^ (rb0 & 7)) * 8)];
      bf16x8 b1 = *(bf16x8*)&Bs[rb1 * 128 + ((ch ^ (rb1 & 7)) * 8)];
      acc[0][0] = __builtin_amdgcn_mfma_f32_16x16x32_bf16(a0, b0, acc[0][0], 0, 0, 0);
      acc[0][1] = __builtin_amdgcn_mfma_f32_16x16x32_bf16(a0, b1, acc[0][1], 0, 0, 0);
      acc[1][0] = __builtin_amdgcn_mfma_f32_16x16x32_bf16(a1, b0, acc[1][0], 0, 0, 0);
      acc[1][1] = __builtin_amdgcn_mfma_f32_16x16x32_bf16(a1, b1, acc[1][1], 0, 0, 0);
    }
  }
  int cl = lane & 15, rq = lane >> 4;
#pragma unroll
  for (int ms = 0; ms < 2; ++ms)
#pragma unroll
    for (int ns = 0; ns < 2; ++ns) {
      int n = n0 + wc * 32 + ns * 16 + cl;
#pragma unroll
      for (int j = 0; j < 4; ++j) {
        int m = m0 + wr * 32 + ms * 16 + rq * 4 + j;
        if (m >= M) continue;
        Cout[(size_t)m * Nn + n] = f2bf(acc[ms][ns][j]);
      }
    }
}

// ---------------- fused readout ----------------
__global__ __launch_bounds__(256) void readout_kernel(
    const ushort* __restrict__ sbf, const ushort* __restrict__ r1T, const float* __restrict__ rb1,
    const float* __restrict__ r_w2, const float* __restrict__ r_b2, const int* __restrict__ bidx,
    float* __restrict__ out, int N, int G) {
  __shared__ ushort As[64 * 128];
  __shared__ ushort Bs[64 * 128];
  __shared__ float rs[64];
  __shared__ float sm[64];
  int tid = threadIdx.x;
  int m0 = blockIdx.x * 64;
  int lane = tid & 63, w = tid >> 6, wr = w >> 1, wc = w & 1;
  int cl = lane & 15, rq = lane >> 4;
#pragma unroll
  for (int r = 0; r < 4; ++r) {
    int c = tid + r * 256;
    int row = c >> 4, ch = c & 15;
    uint4 av = make_uint4(0, 0, 0, 0);
    if (m0 + row < N) av = *(const uint4*)(sbf + (size_t)(m0 + row) * 128 + ch * 8);
    *(uint4*)(&As[row * 128 + ((ch ^ (row & 7)) * 8)]) = av;
    uint4 bv = *(const uint4*)(r1T + (size_t)row * 128 + ch * 8);
    *(uint4*)(&Bs[row * 128 + ((ch ^ (row & 7)) * 8)]) = bv;
  }
  if (tid < 64) {
    rs[tid] = 0.f;
    sm[tid] = 0.f;
  }
  __syncthreads();
  f32x4 acc[2][2] = {};
#pragma unroll
  for (int ks = 0; ks < 4; ++ks) {
    int ch = ks * 4 + rq;
    int ra0 = wr * 32 + cl, ra1 = ra0 + 16;
    int rb0 = wc * 32 + cl, rb1 = rb0 + 16;
    bf16x8 a0 = *(bf16x8*)&As[ra0 * 128 + ((ch ^ (ra0 & 7)) * 8)];
    bf16x8 a1 = *(bf16x8*)&As[ra1 * 128 + ((ch ^ (ra1 & 7)) * 8)];
    bf16x8 b0 = *(bf16x8*)&Bs[rb0 * 128 + ((ch ^ (rb0 & 7)) * 8)];
    bf16x8 b1 = *(bf16x8*)&Bs[rb1 * 128 + ((ch ^ (rb1 & 7)) * 8)];
    acc[0][0] = __builtin_amdgcn_mfma_f32_16x16x32_bf16(a0, b0, acc[0][0], 0, 0, 0);
    acc[0][1] = __builtin_amdgcn_mfma_f32_16x16x32_bf16(a0, b1, acc[0][1], 0, 0, 0);
    acc[1][0] = __builtin_amdgcn_mfma_f32_16x16x32_bf16(a1, b0, acc[1][0], 0, 0, 0);
    acc[1][1] = __builtin_amdgcn_mfma_f32_16x16x32_bf16(a1, b1, acc[1][1], 0, 0, 0);
  }
#pragma unroll
  for (int ms = 0; ms < 2; ++ms) {
    float part0 = 0.f, part1 = 0.f, part2 = 0.f, part3 = 0.f;
#pragma unroll
    for (int ns = 0; ns < 2; ++ns) {
      int col = wc * 32 + ns * 16 + cl;
      float b1v = rb1[col], wv = r_w2[col];
      part0 += silu_f(acc[ms][ns][0] + b1v) * wv;
      part1 += silu_f(acc[ms][ns][1] + b1v) * wv;
      part2 += silu_f(acc[ms][ns][2] + b1v) * wv;
      part3 += silu_f(acc[ms][ns][3] + b1v) * wv;
    }
#pragma unroll
    for (int o = 1; o < 16; o <<= 1) {
      part0 += __shfl_xor(part0, o);
      part1 += __shfl_xor(part1, o);
      part2 += __shfl_xor(part2, o);
      part3 += __shfl_xor(part3, o);
    }
    if (cl == 0) {
      int rbase = wr * 32 + ms * 16 + rq * 4;
      atomicAdd(&rs[rbase + 0], part0);
      atomicAdd(&rs[rbase + 1], part1);
      atomicAdd(&rs[rbase + 2], part2);
      atomicAdd(&rs[rbase + 3], part3);
    }
  }
  __syncthreads();
  float rb2 = r_b2[0];
  if (tid < 64) {
    int m = m0 + tid;
    if (m < N) atomicAdd(&sm[bidx[m]], rs[tid] + rb2);
  }
  __syncthreads();
  if (tid < G && G <= 64) atomicAdd(&out[tid], sm[tid]);
}

extern "C" void kernel_launch(void* const* d_in, const int* in_sizes, int n_in, void* d_out,
                              int out_size, void* d_ws, size_t ws_size, hipStream_t stream) {
  const int N = in_sizes[0];
  const int E = in_sizes[2] / 2;
  const int G = out_size;

  const int* z = (const int*)d_in[0];
  const float* pos = (const float*)d_in[1];
  const int* ei = (const int*)d_in[2];
  const float* shifts = (const float*)d_in[3];
  const int* bidx = (const int*)d_in[4];
  const float* emb = (const float*)d_in[5];
  const float* m_w1 = (const float*)d_in[6];
  const float* m_b1 = (const float*)d_in[7];
  const float* m_w2 = (const float*)d_in[8];
  const float* m_b2 = (const float*)d_in[9];
  const float* f_w = (const float*)d_in[10];
  const float* f_b = (const float*)d_in[11];
  const float* u_w = (const float*)d_in[12];
  const float* v_w = (const float*)d_in[13];
  const float* up_w1 = (const float*)d_in[14];
  const float* up_b1 = (const float*)d_in[15];
  const float* up_w2 = (const float*)d_in[16];
  const float* up_b2 = (const float*)d_in[17];
  const float* r_w1 = (const float*)d_in[18];
  const float* r_b1 = (const float*)d_in[19];
  const float* r_w2 = (const float*)d_in[20];
  const float* r_b2 = (const float*)d_in[21];
  float* out = (float*)d_out;

  float* w = (float*)d_ws;
  size_t off = 0;
  auto alloc = [&](size_t nfl) { float* p = w + off; off += (nfl + 3) & ~(size_t)3; return p; };
  uchar* tab8 = (uchar*)alloc((size_t)3 * TL * 128);
  float* scalar = alloc((size_t)N * 128);
  ushort* sbf = (ushort*)alloc((size_t)N * 64);
  float* vec = alloc((size_t)N * 384);
  uchar* hv8 = (uchar*)alloc((size_t)N * 192);
  ushort* mir_bf = (ushort*)alloc((size_t)N * 192);
  ushort* uvvv = (ushort*)alloc((size_t)N * 384);
  float* pkf = alloc((size_t)E * 4);
  ushort* wt = (ushort*)alloc((size_t)274432);
  int* counts = (int*)alloc((size_t)N);
  int* offs = (int*)alloc((size_t)N + 4);
  int* cursor = (int*)alloc((size_t)N);
  int* order = (int*)alloc((size_t)N);
  if (off * sizeof(float) > ws_size) return;

  hipMemsetAsync(counts, 0, (size_t)N * sizeof(int), stream);
  hipMemsetAsync(out, 0, (size_t)G * sizeof(float), stream);

  table_kernel<<<3 * (TL / 8), 384, 0, stream>>>(f_w, f_b, tab8);
  int nbEmb = (N * 128 + 255) / 256;
  int nbW = (548864 + 255) / 256;
  int nbCount = (E + 255) / 256;
  init_kernel<<<nbEmb + nbW + nbCount, 256, 0, stream>>>(z, emb, scalar, sbf, m_w1, m_w2, u_w,
                                                         v_w, up_w1, up_w2, r_w1, wt, pos, ei,
                                                         shifts, counts, N, E);
  scan_kernel<<<1, 1024, 0, stream>>>(counts, offs, cursor, order, N);
  fill_kernel<<<(E + 255) / 256, 256, 0, stream>>>(pos, ei, shifts, cursor, (float4*)pkf, E);

  dim3 gm((N + 31) / 32);
  dim3 gm2((N + 15) / 16);
  dim3 g3((3 * N + 63) / 64, 4);

  mlp_kernel<<<gm, 512, 0, stream>>>(sbf, wt, m_b1, wt + 16384, m_b2, hv8, N);

  for (int l = 0; l < 3; l++) {
    const ushort* wl = wt + (size_t)l * 180224;
    if (l == 0)
      message_kernel<true><<<(N + 3) / 4, 256, 0, stream>>>(
          offs, order, (const float4*)pkf, hv8, tab8 + (size_t)l * TL * 512, scalar, sbf, vec,
          mir_bf, N);
    else
      message_kernel<false><<<(N + 3) / 4, 256, 0, stream>>>(
          offs, order, (const float4*)pkf, hv8, tab8 + (size_t)l * TL * 512, scalar, sbf, vec,
          mir_bf, N);
    gemm_kernel<<<g3, 256, 0, stream>>>(mir_bf, wl + 65536, uvvv, 3 * N, 128, 256);
    if (l < 2) {
      const ushort* wn = wt + (size_t)(l + 1) * 180224;
      mlp2_kernel<false><<<gm2, 512, 0, stream>>>(
          sbf, wl + 98304, up_b1 + l * 128, wl + 131072, up_b2 + l * 384, uvvv, scalar, sbf, vec,
          hv8, wn, m_b1 + (l + 1) * 128, wn + 16384, m_b2 + (l + 1) * 384, N);
    } else {
      mlp2_kernel<true><<<gm2, 512, 0, stream>>>(
          sbf, wl + 98304, up_b1 + l * 128, wl + 131072, up_b2 + l * 384, uvvv, scalar, sbf, vec,
          hv8, wt, m_b1, wt, m_b2, N);
    }
  }

  readout_kernel<<<(N + 63) / 64, 256, 0, stream>>>(sbf, wt + 540672, r_b1, r_w2, r_b2, bidx,
                                                    out, N, G);
}

// Round 19
// 300.750 us; speedup vs baseline: 1.0227x; 1.0227x over previous
//
#include <hip/hip_runtime.h>
#include <math.h>

#define CUTR 5.0f
#define TL 2048
#define NBASIS 32
#define HSC 16.0f
#define TSC 16.0f
#define VSC 64.0f
#define INV_HT (1.0f / (HSC * TSC))
#define INV_HTV (1.0f / (HSC * TSC * VSC))

typedef __attribute__((ext_vector_type(8))) short bf16x8;
typedef __attribute__((ext_vector_type(4))) float f32x4;
typedef __attribute__((ext_vector_type(2))) float f32x2;

struct U3 { uint x, y, z; };
struct U2 { uint x, y; };

__device__ __forceinline__ float silu_f(float x) { return x / (1.0f + expf(-x)); }
__device__ __forceinline__ ushort f2bf(float x) {
  uint b = __float_as_uint(x);
  uint r = (b + 0x7FFFu + ((b >> 16) & 1u)) >> 16;
  return (ushort)r;
}
__device__ __forceinline__ float bf2f(ushort u) { return __uint_as_float((uint)u << 16); }
__device__ __forceinline__ uchar f2fp8(float x) {
  return (uchar)(__builtin_amdgcn_cvt_pk_fp8_f32(x, 0.0f, 0, false) & 0xff);
}
__device__ __forceinline__ f32x2 fp8lo(uint u) {
  return __builtin_amdgcn_cvt_pk_f32_fp8((int)u, false);
}
__device__ __forceinline__ f32x2 fp8hi(uint u) {
  return __builtin_amdgcn_cvt_pk_f32_fp8((int)u, true);
}

// ---------------- radial table (fp8, interleaved) ----------------
__global__ __launch_bounds__(384) void table_kernel(const float* __restrict__ f_w,
                                                    const float* __restrict__ f_b,
                                                    uchar* __restrict__ tab) {
  __shared__ float fws[NBASIS * 384];
  __shared__ float rbf[8][NBASIS];
  __shared__ float gv[8];
  int tid = threadIdx.x;
  int bi = blockIdx.x;
  int l = bi >> 8, tb = bi & 255;
  for (int i = tid; i < NBASIS * 384; i += 384) fws[i] = f_w[l * NBASIS * 384 + i];
  if (tid < 256) {
    int tt = tid >> 5, k = tid & 31;
    float len = (float)(tb * 8 + tt) * (CUTR / (float)(TL - 1));
    const float gamma = (31.0f / 5.0f) * (31.0f / 5.0f);
    float c = 5.0f * (float)k / 31.0f;
    float d = len - c;
    rbf[tt][k] = expf(-gamma * d * d);
    if (k == 0) {
      float s = len * (1.0f / CUTR);
      gv[tt] = (s < 1.0f) ? expf(1.0f - 1.0f / (1.0f - s * s)) : 0.0f;
    }
  }
  __syncthreads();
  int j = tid % 384;
  int b = j >> 7, ch = j & 127;
  float fb = f_b[l * 384 + j];
  for (int tt = 0; tt < 8; ++tt) {
    float acc = 0.0f;
#pragma unroll
    for (int k = 0; k < NBASIS; ++k) acc += rbf[tt][k] * fws[k * 384 + j];
    float g = gv[tt];
    tab[((size_t)l * TL + (size_t)(tb * 8 + tt)) * 512 + (ch >> 1) * 8 + b * 2 + (ch & 1)] =
        f2fp8(g * (g * acc + fb) * TSC);
  }
}

// ---------------- init: emb | wconv | count (no LDS) ----------------
__global__ __launch_bounds__(256) void init_kernel(
    const int* __restrict__ z, const float* __restrict__ emb, float* __restrict__ scalar,
    ushort* __restrict__ sbf, const float* __restrict__ m_w1, const float* __restrict__ m_w2,
    const float* __restrict__ u_w, const float* __restrict__ v_w,
    const float* __restrict__ up_w1, const float* __restrict__ up_w2,
    const float* __restrict__ r_w1, ushort* __restrict__ wt, const float* __restrict__ pos,
    const int* __restrict__ ei, const float* __restrict__ shifts, int* __restrict__ counts,
    int N, int E) {
  int tid = threadIdx.x;
  int bi = blockIdx.x;
  int nbEmb = (N * 128 + 255) / 256;
  int nbW = (548864 + 255) / 256;
  if (bi < nbEmb) {
    int idx = bi * 256 + tid;
    if (idx >= N * 128) return;
    int n = idx >> 7, j = idx & 127;
    float v = emb[z[n] * 128 + j];
    scalar[idx] = v;
    sbf[idx] = f2bf(v);
    return;
  }
  bi -= nbEmb;
  if (bi < nbW) {
    int idx = bi * 256 + tid;
    if (idx >= 548864) return;
    float v;
    if (idx >= 540672) {
      int t = idx - 540672;
      int n = t >> 7, k = t & 127;
      v = r_w1[k * 64 + n];
    } else {
      int l = idx / 180224, local = idx % 180224;
      if (local < 16384) {
        int n = local >> 7, k = local & 127;
        v = m_w1[l * 16384 + k * 128 + n];
      } else if (local < 65536) {
        int t = local - 16384;
        int n = t >> 7, k = t & 127;
        v = m_w2[l * 49152 + k * 384 + n];
      } else if (local < 98304) {
        int t = local - 65536;
        int n = t >> 7, k = t & 127;
        v = (n < 128) ? u_w[l * 16384 + k * 128 + n] : v_w[l * 16384 + k * 128 + (n - 128)];
      } else if (local < 131072) {
        int t = local - 98304;
        int n = t >> 8, k = t & 255;
        v = up_w1[l * 32768 + k * 128 + n];
      } else {
        int t = local - 131072;
        int n = t >> 7, k = t & 127;
        v = up_w2[l * 49152 + k * 384 + n];
      }
    }
    wt[idx] = f2bf(v);
    return;
  }
  bi -= nbW;
  {
    int e = bi * 256 + tid;
    if (e >= E) return;
    int r = ei[e], c = ei[E + e];
    float dx = pos[c * 3 + 0] - pos[r * 3 + 0] + shifts[e * 3 + 0];
    float dy = pos[c * 3 + 1] - pos[r * 3 + 1] + shifts[e * 3 + 1];
    float dz = pos[c * 3 + 2] - pos[r * 3 + 2] + shifts[e * 3 + 2];
    float len = sqrtf(dx * dx + dy * dy + dz * dz + 1e-12f);
    if (len < CUTR) atomicAdd(&counts[r], 1);
  }
}

// ---------------- scan + descending-degree order ----------------
__global__ __launch_bounds__(1024) void scan_kernel(const int* __restrict__ counts,
                                                    int* __restrict__ offs,
                                                    int* __restrict__ cursor,
                                                    int* __restrict__ order, int N) {
  __shared__ int sm[1024];
  __shared__ int hist[128];
  __shared__ int hoff[128];
  int tid = threadIdx.x;
  int CH = (N + 1023) / 1024;
  int base = tid * CH;
  int sum = 0;
  for (int i = 0; i < CH; i++) sum += (base + i < N) ? counts[base + i] : 0;
  sm[tid] = sum;
  __syncthreads();
  for (int o = 1; o < 1024; o <<= 1) {
    int v = (tid >= o) ? sm[tid - o] : 0;
    __syncthreads();
    sm[tid] += v;
    __syncthreads();
  }
  int run = sm[tid] - sum;
  for (int i = 0; i < CH; i++) {
    if (base + i < N) {
      offs[base + i] = run;
      cursor[base + i] = run;
      run += counts[base + i];
    }
  }
  if (tid == 1023) offs[N] = sm[1023];
  if (tid < 128) hist[tid] = 0;
  __syncthreads();
  for (int i = 0; i < CH; i++) {
    int n = base + i;
    if (n < N) {
      int d = counts[n];
      if (d > 127) d = 127;
      atomicAdd(&hist[d], 1);
    }
  }
  __syncthreads();
  if (tid == 0) {
    int r = 0;
    for (int d = 127; d >= 0; --d) {
      hoff[d] = r;
      r += hist[d];
    }
  }
  __syncthreads();
  for (int i = 0; i < CH; i++) {
    int n = base + i;
    if (n < N) {
      int d = counts[n];
      if (d > 127) d = 127;
      int pos = atomicAdd(&hoff[d], 1);
      order[pos] = n;
    }
  }
}

__global__ void fill_kernel(const float* __restrict__ pos, const int* __restrict__ ei,
                            const float* __restrict__ shifts, int* __restrict__ cursor,
                            float4* __restrict__ pk, int E) {
  int e = blockIdx.x * 256 + threadIdx.x;
  if (e >= E) return;
  int r = ei[e], c = ei[E + e];
  float dx = pos[c * 3 + 0] - pos[r * 3 + 0] + shifts[e * 3 + 0];
  float dy = pos[c * 3 + 1] - pos[r * 3 + 1] + shifts[e * 3 + 1];
  float dz = pos[c * 3 + 2] - pos[r * 3 + 2] + shifts[e * 3 + 2];
  float len = sqrtf(dx * dx + dy * dy + dz * dz + 1e-12f);
  if (len >= CUTR) return;
  float inv = 1.0f / len;
  float x = len * ((float)(TL - 1) / CUTR);
  int ib = (int)(x + 0.5f);
  if (ib > TL - 1) ib = TL - 1;
  int p = atomicAdd(&cursor[r], 1);
  pk[p] = make_float4(__int_as_float(c | (ib << 14)), dx * inv, dy * inv, dz * inv);
}

// ---------------- fused message: 1 wave/node (degree-sorted), fp8 gathers, packed math -----
template <bool FIRST>
__global__ __launch_bounds__(256) void message_kernel(
    const int* __restrict__ offs, const int* __restrict__ order, const float4* __restrict__ pk,
    const uchar* __restrict__ hv8, const uchar* __restrict__ tab8, float* __restrict__ scalar,
    ushort* __restrict__ sbf, float* __restrict__ vec, ushort* __restrict__ vbout, int N) {
  int lane = threadIdx.x & 63;
  int idx = blockIdx.x * 4 + (threadIdx.x >> 6);
  if (idx >= N) return;
  int n = order[idx];
  int p0 = offs[n], p1 = offs[n + 1];
  f32x2 aS = {0.f, 0.f};
  f32x2 aW0 = {0.f, 0.f}, aW1 = {0.f, 0.f}, aW2 = {0.f, 0.f};
  f32x2 aD0 = {0.f, 0.f}, aD1 = {0.f, 0.f}, aD2 = {0.f, 0.f};
  int p = p0;
  bool hasA = p < p1, hasB = p + 1 < p1;
  float4 cA, cB;
  if (hasA) cA = pk[p];
  if (hasB) cB = pk[p + 1];
  while (hasA) {
    int bitsA = __float_as_int(cA.x);
    int colA = bitsA & 16383, ibA = bitsA >> 14;
    U3 hvA;
    if (FIRST) {
      U2 t = *(const U2*)(hv8 + (size_t)colA * 768 + lane * 12);
      hvA.x = t.x; hvA.y = t.y; hvA.z = 0;
    } else {
      hvA = *(const U3*)(hv8 + (size_t)colA * 768 + lane * 12);
    }
    U2 tA = *(const U2*)(tab8 + (size_t)ibA * 512 + lane * 8);
    U3 hvB;
    U2 tB;
    float4 dB;
    if (hasB) {
      int bitsB = __float_as_int(cB.x);
      int colB = bitsB & 16383, ibB = bitsB >> 14;
      dB = cB;
      if (FIRST) {
        U2 t = *(const U2*)(hv8 + (size_t)colB * 768 + lane * 12);
        hvB.x = t.x; hvB.y = t.y; hvB.z = 0;
      } else {
        hvB = *(const U3*)(hv8 + (size_t)colB * 768 + lane * 12);
      }
      tB = *(const U2*)(tab8 + (size_t)ibB * 512 + lane * 8);
    }
    int pn = p + 2;
    bool nA = pn < p1, nB = pn + 1 < p1;
    float4 fA, fB;
    if (nA) fA = pk[pn];
    if (nB) fB = pk[pn + 1];
    {
      f32x2 h1 = fp8lo(hvA.x), h2 = fp8hi(hvA.x);
      f32x2 h3 = fp8lo(hvA.y);
      f32x2 t1 = fp8lo(tA.x), t2 = fp8hi(tA.x), t3 = fp8lo(tA.y);
      aS += h1 * t1;
      f32x2 w3 = h3 * t3;
      if (!FIRST) {
        f32x2 v0 = fp8hi(hvA.y), v1 = fp8lo(hvA.z), v2 = fp8hi(hvA.z);
        f32x2 w2 = h2 * t2;
        aW0 += v0 * w2;
        aW1 += v1 * w2;
        aW2 += v2 * w2;
      }
      aD0 += w3 * cA.y;
      aD1 += w3 * cA.z;
      aD2 += w3 * cA.w;
    }
    if (hasB) {
      f32x2 h1 = fp8lo(hvB.x), h2 = fp8hi(hvB.x);
      f32x2 h3 = fp8lo(hvB.y);
      f32x2 t1 = fp8lo(tB.x), t2 = fp8hi(tB.x), t3 = fp8lo(tB.y);
      aS += h1 * t1;
      f32x2 w3 = h3 * t3;
      if (!FIRST) {
        f32x2 v0 = fp8hi(hvB.y), v1 = fp8lo(hvB.z), v2 = fp8hi(hvB.z);
        f32x2 w2 = h2 * t2;
        aW0 += v0 * w2;
        aW1 += v1 * w2;
        aW2 += v2 * w2;
      }
      aD0 += w3 * dB.y;
      aD1 += w3 * dB.z;
      aD2 += w3 * dB.w;
    }
    cA = fA;
    cB = fB;
    hasA = nA;
    hasB = nB;
    p = pn;
  }
  f32x2 sS = aS * INV_HT;
  f32x2 sV0 = aD0 * INV_HT, sV1 = aD1 * INV_HT, sV2 = aD2 * INV_HT;
  if (!FIRST) {
    sV0 += aW0 * INV_HTV;
    sV1 += aW1 * INV_HTV;
    sV2 += aW2 * INV_HTV;
  }
  float2* sp = (float2*)(scalar + (size_t)n * 128) + lane;
  float2 sv = *sp;
  sv.x += sS.x;
  sv.y += sS.y;
  *sp = sv;
  ((uint*)(sbf + (size_t)n * 128))[lane] = (uint)f2bf(sv.x) | ((uint)f2bf(sv.y) << 16);
  float2* vp0 = (float2*)(vec + (size_t)n * 384) + lane;
  float2* vp1 = (float2*)(vec + (size_t)n * 384 + 128) + lane;
  float2* vp2 = (float2*)(vec + (size_t)n * 384 + 256) + lane;
  float2 v0, v1, v2;
  if (FIRST) {
    v0 = make_float2(sV0.x, sV0.y);
    v1 = make_float2(sV1.x, sV1.y);
    v2 = make_float2(sV2.x, sV2.y);
  } else {
    v0 = *vp0; v1 = *vp1; v2 = *vp2;
    v0.x += sV0.x; v0.y += sV0.y;
    v1.x += sV1.x; v1.y += sV1.y;
    v2.x += sV2.x; v2.y += sV2.y;
  }
  *vp0 = v0; *vp1 = v1; *vp2 = v2;
  uint* ob = (uint*)(vbout + (size_t)n * 384);
  ob[lane] = (uint)f2bf(v0.x) | ((uint)f2bf(v0.y) << 16);
  ob[lane + 64] = (uint)f2bf(v1.x) | ((uint)f2bf(v1.y) << 16);
  ob[lane + 128] = (uint)f2bf(v2.x) | ((uint)f2bf(v2.y) << 16);
}

// ---------------- message MLP (layer 0 only): writes h-part of hv8 ----------------
__global__ __launch_bounds__(512) void mlp_kernel(const ushort* __restrict__ A,
                                                  const ushort* __restrict__ W1T,
                                                  const float* __restrict__ b1,
                                                  const ushort* __restrict__ W2T,
                                                  const float* __restrict__ b2,
                                                  uchar* __restrict__ out, int M) {
  __shared__ ushort As[32 * 128];
  __shared__ ushort Bs[128 * 128];
  __shared__ ushort Hs[32 * 128];
  int tid = threadIdx.x;
  int lane = tid & 63, w = tid >> 6;
  int mh = w >> 2, wc = w & 3;
  int m0 = blockIdx.x * 32;
  int cl = lane & 15, rq = lane >> 4;
  int ra = mh * 16 + cl;
  f32x4 acc[2] = {};
  {
    {
      int row = tid >> 4, ch = tid & 15;
      uint4 av = make_uint4(0, 0, 0, 0);
      if (m0 + row < M) av = *(const uint4*)(A + (size_t)(m0 + row) * 128 + ch * 8);
      *(uint4*)(&As[row * 128 + ((ch ^ (row & 7)) * 8)]) = av;
    }
#pragma unroll
    for (int r = 0; r < 4; ++r) {
      int c = tid + r * 512;
      int row = c >> 4, ch = c & 15;
      uint4 bv = *(const uint4*)(W1T + (size_t)row * 128 + ch * 8);
      *(uint4*)(&Bs[row * 128 + ((ch ^ (row & 7)) * 8)]) = bv;
    }
    __syncthreads();
#pragma unroll
    for (int ks = 0; ks < 4; ++ks) {
      int ch = ks * 4 + rq;
      bf16x8 a = *(bf16x8*)&As[ra * 128 + ((ch ^ (ra & 7)) * 8)];
#pragma unroll
      for (int ns = 0; ns < 2; ++ns) {
        int rb = wc * 32 + ns * 16 + cl;
        bf16x8 b = *(bf16x8*)&Bs[rb * 128 + ((ch ^ (rb & 7)) * 8)];
        acc[ns] = __builtin_amdgcn_mfma_f32_16x16x32_bf16(a, b, acc[ns], 0, 0, 0);
      }
    }
  }
#pragma unroll
  for (int ns = 0; ns < 2; ++ns) {
    int hcol = wc * 32 + ns * 16 + cl;
    float bv = b1[hcol];
    int chunk = hcol >> 3, el = hcol & 7;
#pragma unroll
    for (int j = 0; j < 4; ++j) {
      int hr = mh * 16 + rq * 4 + j;
      float v = silu_f(acc[ns][j] + bv);
      Hs[hr * 128 + ((chunk ^ (hr & 7)) * 8) + el] = f2bf(v);
    }
  }
  __syncthreads();
  for (int nt = 0; nt < 3; ++nt) {
#pragma unroll
    for (int r = 0; r < 4; ++r) {
      int c = tid + r * 512;
      int row = c >> 4, ch = c & 15;
      uint4 bv = *(const uint4*)(W2T + (size_t)(nt * 128 + row) * 128 + ch * 8);
      *(uint4*)(&Bs[row * 128 + ((ch ^ (row & 7)) * 8)]) = bv;
    }
    __syncthreads();
    f32x4 acc2[2] = {};
#pragma unroll
    for (int ks = 0; ks < 4; ++ks) {
      int ch = ks * 4 + rq;
      bf16x8 a = *(bf16x8*)&Hs[ra * 128 + ((ch ^ (ra & 7)) * 8)];
#pragma unroll
      for (int ns = 0; ns < 2; ++ns) {
        int rb = wc * 32 + ns * 16 + cl;
        bf16x8 b = *(bf16x8*)&Bs[rb * 128 + ((ch ^ (rb & 7)) * 8)];
        acc2[ns] = __builtin_amdgcn_mfma_f32_16x16x32_bf16(a, b, acc2[ns], 0, 0, 0);
      }
    }
#pragma unroll
    for (int ns = 0; ns < 2; ++ns) {
      int ch = wc * 32 + ns * 16 + cl;
      float bv = b2[nt * 128 + ch];
#pragma unroll
      for (int j = 0; j < 4; ++j) {
        int m = m0 + mh * 16 + rq * 4 + j;
        if (m >= M) continue;
        out[(size_t)m * 768 + (ch >> 1) * 12 + nt * 2 + (ch & 1)] =
            f2fp8((acc2[ns][j] + bv) * HSC);
      }
    }
    __syncthreads();
  }
}

// ---------------- fused update MLP + combine (+ next-layer MLP unless LAST) ----------------
template <bool LAST>
__global__ __launch_bounds__(512) void mlp2_kernel(
    const ushort* __restrict__ sbf_in, const ushort* __restrict__ W1T,
    const float* __restrict__ b1, const ushort* __restrict__ W2T, const float* __restrict__ b2,
    const ushort* __restrict__ uvvv, float* __restrict__ scalar, ushort* __restrict__ sbf,
    float* __restrict__ vec, uchar* __restrict__ hv8, const ushort* __restrict__ W1nT,
    const float* __restrict__ b1n, const ushort* __restrict__ W2nT,
    const float* __restrict__ b2n, int M) {
  __shared__ ushort As[16 * 128];
  __shared__ ushort Bs[128 * 128];
  __shared__ ushort Hs[16 * 128];
  int tid = threadIdx.x;
  int lane = tid & 63, w = tid >> 6;
  int m0 = blockIdx.x * 16;
  int cl = lane & 15, rq = lane >> 4;
  int rb = w * 16 + cl;
  f32x4 acc = {};
  for (int k0 = 0; k0 < 256; k0 += 128) {
    __syncthreads();
    if (tid < 256) {
      int row = tid >> 4, ch = tid & 15;
      uint4 av = make_uint4(0, 0, 0, 0);
      if (m0 + row < M) {
        if (k0 == 0) {
          av = *(const uint4*)(sbf_in + (size_t)(m0 + row) * 128 + ch * 8);
        } else {
          const ushort* ub = uvvv + (size_t)(m0 + row) * 768 + 128 + ch * 8;
          bf16x8 x0 = *(const bf16x8*)(ub);
          bf16x8 x1 = *(const bf16x8*)(ub + 256);
          bf16x8 x2 = *(const bf16x8*)(ub + 512);
          ushort pkv[8];
#pragma unroll
          for (int e = 0; e < 8; ++e) {
            float a = bf2f((ushort)x0[e]), bb = bf2f((ushort)x1[e]), cc = bf2f((ushort)x2[e]);
            pkv[e] = f2bf(sqrtf(a * a + bb * bb + cc * cc + 1e-8f));
          }
          av = *(uint4*)pkv;
        }
      }
      *(uint4*)(&As[row * 128 + ((ch ^ (row & 7)) * 8)]) = av;
    }
#pragma unroll
    for (int r = 0; r < 4; ++r) {
      int c = tid + r * 512;
      int row = c >> 4, ch = c & 15;
      uint4 bv = *(const uint4*)(W1T + (size_t)row * 256 + k0 + ch * 8);
      *(uint4*)(&Bs[row * 128 + ((ch ^ (row & 7)) * 8)]) = bv;
    }
    __syncthreads();
#pragma unroll
    for (int ks = 0; ks < 4; ++ks) {
      int ch = ks * 4 + rq;
      bf16x8 a = *(bf16x8*)&As[cl * 128 + ((ch ^ (cl & 7)) * 8)];
      bf16x8 b = *(bf16x8*)&Bs[rb * 128 + ((ch ^ (rb & 7)) * 8)];
      acc = __builtin_amdgcn_mfma_f32_16x16x32_bf16(a, b, acc, 0, 0, 0);
    }
  }
  {
    int hcol = w * 16 + cl;
    float bv = b1[hcol];
    int chunk = hcol >> 3, el = hcol & 7;
#pragma unroll
    for (int j = 0; j < 4; ++j) {
      int hr = rq * 4 + j;
      Hs[hr * 128 + ((chunk ^ (hr & 7)) * 8) + el] = f2bf(silu_f(acc[j] + bv));
    }
  }
  __syncthreads();
  f32x4 aReg[3];
  for (int nt = 0; nt < 3; ++nt) {
#pragma unroll
    for (int r = 0; r < 4; ++r) {
      int c = tid + r * 512;
      int row = c >> 4, ch = c & 15;
      uint4 bv = *(const uint4*)(W2T + (size_t)(nt * 128 + row) * 128 + ch * 8);
      *(uint4*)(&Bs[row * 128 + ((ch ^ (row & 7)) * 8)]) = bv;
    }
    __syncthreads();
    f32x4 acc2 = {};
#pragma unroll
    for (int ks = 0; ks < 4; ++ks) {
      int ch = ks * 4 + rq;
      bf16x8 a = *(bf16x8*)&Hs[cl * 128 + ((ch ^ (cl & 7)) * 8)];
      bf16x8 b = *(bf16x8*)&Bs[rb * 128 + ((ch ^ (rb & 7)) * 8)];
      acc2 = __builtin_amdgcn_mfma_f32_16x16x32_bf16(a, b, acc2, 0, 0, 0);
    }
    aReg[nt] = acc2;
    __syncthreads();
  }
  {
    int chOff = w * 16 + cl;
    float b2a = b2[chOff], b2b = b2[128 + chOff], b2c = b2[256 + chOff];
#pragma unroll
    for (int j = 0; j < 4; ++j) {
      int nn = m0 + rq * 4 + j;
      if (nn >= M) continue;
      float a1 = aReg[0][j] + b2a;
      float a2 = aReg[1][j] + b2b;
      float a3 = aReg[2][j] + b2c;
      const ushort* ub = uvvv + (size_t)nn * 768;
      float uv0 = bf2f(ub[chOff]), vv0 = bf2f(ub[128 + chOff]);
      float uv1 = bf2f(ub[256 + chOff]), vv1 = bf2f(ub[384 + chOff]);
      float uv2 = bf2f(ub[512 + chOff]), vv2 = bf2f(ub[640 + chOff]);
      float dot = uv0 * vv0 + uv1 * vv1 + uv2 * vv2;
      size_t si = (size_t)nn * 128 + chOff;
      float s = scalar[si] + a1 + a2 * dot;
      scalar[si] = s;
      ushort sb = f2bf(s);
      sbf[si] = sb;
      if (!LAST) {
        int lr = rq * 4 + j;
        As[lr * 128 + (((chOff >> 3) ^ (lr & 7)) * 8) + (chOff & 7)] = sb;
        size_t vb = (size_t)nn * 384 + chOff;
        float nv0 = vec[vb] + a3 * uv0;
        float nv1 = vec[vb + 128] + a3 * uv1;
        float nv2 = vec[vb + 256] + a3 * uv2;
        vec[vb] = nv0;
        vec[vb + 128] = nv1;
        vec[vb + 256] = nv2;
        size_t hb = (size_t)nn * 768 + (chOff >> 1) * 12 + 6 + (chOff & 1);
        hv8[hb] = f2fp8(nv0 * VSC);
        hv8[hb + 2] = f2fp8(nv1 * VSC);
        hv8[hb + 4] = f2fp8(nv2 * VSC);
      }
    }
  }
  if (LAST) return;
#pragma unroll
  for (int r = 0; r < 4; ++r) {
    int c = tid + r * 512;
    int row = c >> 4, ch = c & 15;
    uint4 bv = *(const uint4*)(W1nT + (size_t)row * 128 + ch * 8);
    *(uint4*)(&Bs[row * 128 + ((ch ^ (row & 7)) * 8)]) = bv;
  }
  __syncthreads();
  f32x4 acc3 = {};
#pragma unroll
  for (int ks = 0; ks < 4; ++ks) {
    int ch = ks * 4 + rq;
    bf16x8 a = *(bf16x8*)&As[cl * 128 + ((ch ^ (cl & 7)) * 8)];
    bf16x8 b = *(bf16x8*)&Bs[rb * 128 + ((ch ^ (rb & 7)) * 8)];
    acc3 = __builtin_amdgcn_mfma_f32_16x16x32_bf16(a, b, acc3, 0, 0, 0);
  }
  __syncthreads();
  {
    int hcol = w * 16 + cl;
    float bv = b1n[hcol];
    int chunk = hcol >> 3, el = hcol & 7;
#pragma unroll
    for (int j = 0; j < 4; ++j) {
      int hr = rq * 4 + j;
      Hs[hr * 128 + ((chunk ^ (hr & 7)) * 8) + el] = f2bf(silu_f(acc3[j] + bv));
    }
  }
  __syncthreads();
  for (int nt = 0; nt < 3; ++nt) {
#pragma unroll
    for (int r = 0; r < 4; ++r) {
      int c = tid + r * 512;
      int row = c >> 4, ch = c & 15;
      uint4 bv = *(const uint4*)(W2nT + (size_t)(nt * 128 + row) * 128 + ch * 8);
      *(uint4*)(&Bs[row * 128 + ((ch ^ (row & 7)) * 8)]) = bv;
    }
    __syncthreads();
    f32x4 acc4 = {};
#pragma unroll
    for (int ks = 0; ks < 4; ++ks) {
      int ch = ks * 4 + rq;
      bf16x8 a = *(bf16x8*)&Hs[cl * 128 + ((ch ^ (cl & 7)) * 8)];
      bf16x8 b = *(bf16x8*)&Bs[rb * 128 + ((ch ^ (rb & 7)) * 8)];
      acc4 = __builtin_amdgcn_mfma_f32_16x16x32_bf16(a, b, acc4, 0, 0, 0);
    }
    {
      int ch = w * 16 + cl;
      float bv = b2n[nt * 128 + ch];
#pragma unroll
      for (int j = 0; j < 4; ++j) {
        int m = m0 + rq * 4 + j;
        if (m >= M) continue;
        hv8[(size_t)m * 768 + (ch >> 1) * 12 + nt * 2 + (ch & 1)] =
            f2fp8((acc4[j] + bv) * HSC);
      }
    }
    __syncthreads();
  }
}

// ---------------- bf16 MFMA GEMM: C = A[M,K] @ WT[N,K]^T -> bf16 ----------------
__global__ __launch_bounds__(256) void gemm_kernel(const ushort* __restrict__ A,
                                                   const ushort* __restrict__ WT,
                                                   ushort* __restrict__ Cout, int M, int K,
                                                   int Nn) {
  __shared__ ushort As[64 * 128];
  __shared__ ushort Bs[64 * 128];
  int tid = threadIdx.x;
  int m0 = blockIdx.x * 64, n0 = blockIdx.y * 64;
  int lane = tid & 63, w = tid >> 6, wr = w >> 1, wc = w & 1;
  f32x4 acc[2][2] = {};
  for (int k0 = 0; k0 < K; k0 += 128) {
    __syncthreads();
#pragma unroll
    for (int r = 0; r < 4; ++r) {
      int c = tid + r * 256;
      int row = c >> 4, col16 = c & 15;
      uint4 av = make_uint4(0, 0, 0, 0);
      if (m0 + row < M) av = *(const uint4*)(A + (size_t)(m0 + row) * K + k0 + col16 * 8);
      *(uint4*)(&As[row * 128 + ((col16 ^ (row & 7)) * 8)]) = av;
      uint4 bv = *(const uint4*)(WT + (size_t)(n0 + row) * K + k0 + col16 * 8);
      *(uint4*)(&Bs[row * 128 + ((col16 ^ (row & 7)) * 8)]) = bv;
    }
    __syncthreads();
#pragma unroll
    for (int ks = 0; ks < 4; ++ks) {
      int ch = ks * 4 + (lane >> 4);
      int ra0 = wr * 32 + (lane & 15), ra1 = ra0 + 16;
      int rb0 = wc * 32 + (lane & 15), rb1 = rb0 + 16;
      bf16x8 a0 = *(bf16x8*)&As[ra0 * 128 + ((ch ^ (ra0 & 7)) * 8)];
      bf16x8 a1 = *(bf16x8*)&As[ra1 * 128 + ((ch ^ (ra1 & 7)) * 8)];
      bf16x8 b0 = *(bf16x8*)&Bs[rb0 * 128 + ((ch ^ (rb0 & 7)) * 8)];
      bf16x8 b1 = *(bf16x8*)&Bs[rb1 * 128 + ((ch ^ (rb1 & 7)) * 8)];
      acc[0][0] = __builtin_amdgcn_mfma_f32_16x16x32_bf16(a0, b0, acc[0][0], 0, 0, 0);
      acc[0][1] = __builtin_amdgcn_mfma_f32_16x16x32_bf16(a0, b1, acc[0][1], 0, 0, 0);
      acc[1][0] = __builtin_amdgcn_mfma_f32_16x16x32_bf16(a1, b0, acc[1][0], 0, 0, 0);
      acc[1][1] = __builtin_amdgcn_mfma_f32_16x16x32_bf16(a1, b1, acc[1][1], 0, 0, 0);
    }
  }
  int cl = lane & 15, rq = lane >> 4;
#pragma unroll
  for (int ms = 0; ms < 2; ++ms)
#pragma unroll
    for (int ns = 0; ns < 2; ++ns) {
      int n = n0 + wc * 32 + ns * 16 + cl;
#pragma unroll
      for (int j = 0; j < 4; ++j) {
        int m = m0 + wr * 32 + ms * 16 + rq * 4 + j;
        if (m >= M) continue;
        Cout[(size_t)m * Nn + n] = f2bf(acc[ms][ns][j]);
      }
    }
}

// ---------------- fused readout ----------------
__global__ __launch_bounds__(256) void readout_kernel(
    const ushort* __restrict__ sbf, const ushort* __restrict__ r1T, const float* __restrict__ rb1,
    const float* __restrict__ r_w2, const float* __restrict__ r_b2, const int* __restrict__ bidx,
    float* __restrict__ out, int N, int G) {
  __shared__ ushort As[64 * 128];
  __shared__ ushort Bs[64 * 128];
  __shared__ float rs[64];
  __shared__ float sm[64];
  int tid = threadIdx.x;
  int m0 = blockIdx.x * 64;
  int lane = tid & 63, w = tid >> 6, wr = w >> 1, wc = w & 1;
  int cl = lane & 15, rq = lane >> 4;
#pragma unroll
  for (int r = 0; r < 4; ++r) {
    int c = tid + r * 256;
    int row = c >> 4, ch = c & 15;
    uint4 av = make_uint4(0, 0, 0, 0);
    if (m0 + row < N) av = *(const uint4*)(sbf + (size_t)(m0 + row) * 128 + ch * 8);
    *(uint4*)(&As[row * 128 + ((ch ^ (row & 7)) * 8)]) = av;
    uint4 bv = *(const uint4*)(r1T + (size_t)row * 128 + ch * 8);
    *(uint4*)(&Bs[row * 128 + ((ch ^ (row & 7)) * 8)]) = bv;
  }
  if (tid < 64) {
    rs[tid] = 0.f;
    sm[tid] = 0.f;
  }
  __syncthreads();
  f32x4 acc[2][2] = {};
#pragma unroll
  for (int ks = 0; ks < 4; ++ks) {
    int ch = ks * 4 + rq;
    int ra0 = wr * 32 + cl, ra1 = ra0 + 16;
    int rb0 = wc * 32 + cl, rb1 = rb0 + 16;
    bf16x8 a0 = *(bf16x8*)&As[ra0 * 128 + ((ch ^ (ra0 & 7)) * 8)];
    bf16x8 a1 = *(bf16x8*)&As[ra1 * 128 + ((ch ^ (ra1 & 7)) * 8)];
    bf16x8 b0 = *(bf16x8*)&Bs[rb0 * 128 + ((ch ^ (rb0 & 7)) * 8)];
    bf16x8 b1 = *(bf16x8*)&Bs[rb1 * 128 + ((ch ^ (rb1 & 7)) * 8)];
    acc[0][0] = __builtin_amdgcn_mfma_f32_16x16x32_bf16(a0, b0, acc[0][0], 0, 0, 0);
    acc[0][1] = __builtin_amdgcn_mfma_f32_16x16x32_bf16(a0, b1, acc[0][1], 0, 0, 0);
    acc[1][0] = __builtin_amdgcn_mfma_f32_16x16x32_bf16(a1, b0, acc[1][0], 0, 0, 0);
    acc[1][1] = __builtin_amdgcn_mfma_f32_16x16x32_bf16(a1, b1, acc[1][1], 0, 0, 0);
  }
#pragma unroll
  for (int ms = 0; ms < 2; ++ms) {
    float part0 = 0.f, part1 = 0.f, part2 = 0.f, part3 = 0.f;
#pragma unroll
    for (int ns = 0; ns < 2; ++ns) {
      int col = wc * 32 + ns * 16 + cl;
      float b1v = rb1[col], wv = r_w2[col];
      part0 += silu_f(acc[ms][ns][0] + b1v) * wv;
      part1 += silu_f(acc[ms][ns][1] + b1v) * wv;
      part2 += silu_f(acc[ms][ns][2] + b1v) * wv;
      part3 += silu_f(acc[ms][ns][3] + b1v) * wv;
    }
#pragma unroll
    for (int o = 1; o < 16; o <<= 1) {
      part0 += __shfl_xor(part0, o);
      part1 += __shfl_xor(part1, o);
      part2 += __shfl_xor(part2, o);
      part3 += __shfl_xor(part3, o);
    }
    if (cl == 0) {
      int rbase = wr * 32 + ms * 16 + rq * 4;
      atomicAdd(&rs[rbase + 0], part0);
      atomicAdd(&rs[rbase + 1], part1);
      atomicAdd(&rs[rbase + 2], part2);
      atomicAdd(&rs[rbase + 3], part3);
    }
  }
  __syncthreads();
  float rb2 = r_b2[0];
  if (tid < 64) {
    int m = m0 + tid;
    if (m < N) atomicAdd(&sm[bidx[m]], rs[tid] + rb2);
  }
  __syncthreads();
  if (tid < G && G <= 64) atomicAdd(&out[tid], sm[tid]);
}

extern "C" void kernel_launch(void* const* d_in, const int* in_sizes, int n_in, void* d_out,
                              int out_size, void* d_ws, size_t ws_size, hipStream_t stream) {
  const int N = in_sizes[0];
  const int E = in_sizes[2] / 2;
  const int G = out_size;

  const int* z = (const int*)d_in[0];
  const float* pos = (const float*)d_in[1];
  const int* ei = (const int*)d_in[2];
  const float* shifts = (const float*)d_in[3];
  const int* bidx = (const int*)d_in[4];
  const float* emb = (const float*)d_in[5];
  const float* m_w1 = (const float*)d_in[6];
  const float* m_b1 = (const float*)d_in[7];
  const float* m_w2 = (const float*)d_in[8];
  const float* m_b2 = (const float*)d_in[9];
  const float* f_w = (const float*)d_in[10];
  const float* f_b = (const float*)d_in[11];
  const float* u_w = (const float*)d_in[12];
  const float* v_w = (const float*)d_in[13];
  const float* up_w1 = (const float*)d_in[14];
  const float* up_b1 = (const float*)d_in[15];
  const float* up_w2 = (const float*)d_in[16];
  const float* up_b2 = (const float*)d_in[17];
  const float* r_w1 = (const float*)d_in[18];
  const float* r_b1 = (const float*)d_in[19];
  const float* r_w2 = (const float*)d_in[20];
  const float* r_b2 = (const float*)d_in[21];
  float* out = (float*)d_out;

  float* w = (float*)d_ws;
  size_t off = 0;
  auto alloc = [&](size_t nfl) { float* p = w + off; off += (nfl + 3) & ~(size_t)3; return p; };
  uchar* tab8 = (uchar*)alloc((size_t)3 * TL * 128);
  float* scalar = alloc((size_t)N * 128);
  ushort* sbf = (ushort*)alloc((size_t)N * 64);
  float* vec = alloc((size_t)N * 384);
  uchar* hv8 = (uchar*)alloc((size_t)N * 192);
  ushort* mir_bf = (ushort*)alloc((size_t)N * 192);
  ushort* uvvv = (ushort*)alloc((size_t)N * 384);
  float* pkf = alloc((size_t)E * 4);
  ushort* wt = (ushort*)alloc((size_t)274432);
  int* counts = (int*)alloc((size_t)N);
  int* offs = (int*)alloc((size_t)N + 4);
  int* cursor = (int*)alloc((size_t)N);
  int* order = (int*)alloc((size_t)N);
  if (off * sizeof(float) > ws_size) return;

  hipMemsetAsync(counts, 0, (size_t)N * sizeof(int), stream);
  hipMemsetAsync(out, 0, (size_t)G * sizeof(float), stream);

  table_kernel<<<3 * (TL / 8), 384, 0, stream>>>(f_w, f_b, tab8);
  int nbEmb = (N * 128 + 255) / 256;
  int nbW = (548864 + 255) / 256;
  int nbCount = (E + 255) / 256;
  init_kernel<<<nbEmb + nbW + nbCount, 256, 0, stream>>>(z, emb, scalar, sbf, m_w1, m_w2, u_w,
                                                         v_w, up_w1, up_w2, r_w1, wt, pos, ei,
                                                         shifts, counts, N, E);
  scan_kernel<<<1, 1024, 0, stream>>>(counts, offs, cursor, order, N);
  fill_kernel<<<(E + 255) / 256, 256, 0, stream>>>(pos, ei, shifts, cursor, (float4*)pkf, E);

  dim3 gm((N + 31) / 32);
  dim3 gm2((N + 15) / 16);
  dim3 g3((3 * N + 63) / 64, 4);

  mlp_kernel<<<gm, 512, 0, stream>>>(sbf, wt, m_b1, wt + 16384, m_b2, hv8, N);

  for (int l = 0; l < 3; l++) {
    const ushort* wl = wt + (size_t)l * 180224;
    if (l == 0)
      message_kernel<true><<<(N + 3) / 4, 256, 0, stream>>>(
          offs, order, (const float4*)pkf, hv8, tab8 + (size_t)l * TL * 512, scalar, sbf, vec,
          mir_bf, N);
    else
      message_kernel<false><<<(N + 3) / 4, 256, 0, stream>>>(
          offs, order, (const float4*)pkf, hv8, tab8 + (size_t)l * TL * 512, scalar, sbf, vec,
          mir_bf, N);
    gemm_kernel<<<g3, 256, 0, stream>>>(mir_bf, wl + 65536, uvvv, 3 * N, 128, 256);
    if (l < 2) {
      const ushort* wn = wt + (size_t)(l + 1) * 180224;
      mlp2_kernel<false><<<gm2, 512, 0, stream>>>(
          sbf, wl + 98304, up_b1 + l * 128, wl + 131072, up_b2 + l * 384, uvvv, scalar, sbf, vec,
          hv8, wn, m_b1 + (l + 1) * 128, wn + 16384, m_b2 + (l + 1) * 384, N);
    } else {
      mlp2_kernel<true><<<gm2, 512, 0, stream>>>(
          sbf, wl + 98304, up_b1 + l * 128, wl + 131072, up_b2 + l * 384, uvvv, scalar, sbf, vec,
          hv8, wt, m_b1, wt, m_b2, N);
    }
  }

  readout_kernel<<<(N + 63) / 64, 256, 0, stream>>>(sbf, wt + 540672, r_b1, r_w2, r_b2, bidx,
                                                    out, N, G);
}